// Round 1
// 1236.383 us; speedup vs baseline: 1.0053x; 1.0053x over previous
//
#include <hip/hip_runtime.h>

// VocabParallelEmbeddingWithDelta: out[t,:] = weight[x[t],:] + (indices[t] >= 0
//   ? delta_weights[indices[t], x[t], :] : 0)
// T=8192 tokens, D=2048, fp32. Pure memory-bound double gather + add.
//
// Traffic model: 64 MiB base-row reads (weight, 256 MB table -> LLC-resident,
// duplicate tokens re-hit) + 64 MiB delta-row reads (1 GB table, read-once)
// + 64 MiB output writes (write-once). Roofline ~31 us @ 6.3 TB/s.
//
// This version:
//  - grid-stride persistent blocks: 2048 blocks x 256 thr = 8 blocks/CU x 256 CU,
//    each block handles ~4 tokens; next token's (x, indices) are prefetched one
//    iteration ahead so the dependent id-load -> row-load chain hides under the
//    current row copy.
//  - nontemporal loads for delta rows and nontemporal stores for out: both are
//    touched exactly once, so keep them from evicting the reusable weight table
//    out of L2/LLC.

#define EMBED 2048
#define VOCAB 32000
#define BLOCK 256
#define MAXGRID 2048   // 8 blocks/CU * 256 CU

typedef float f32x4 __attribute__((ext_vector_type(4)));

__global__ __launch_bounds__(BLOCK)
void VocabParallelEmbeddingWithDelta_28973849379098_kernel(
        const int* __restrict__ x,
        const int* __restrict__ indices,
        const float* __restrict__ weight,
        const float* __restrict__ delta_weights,
        float* __restrict__ out,
        const int num_tokens) {
    const int stride = gridDim.x;
    int t = blockIdx.x;
    if (t >= num_tokens) return;

    // Wave-uniform per-token ids, software-prefetched one grid-stride ahead.
    int tok = x[t];
    int ad  = indices[t];

    for (;;) {
        const int  tn       = t + stride;
        const bool has_next = (tn < num_tokens);
        int ntok = 0, nad = 0;
        if (has_next) {           // issue early: latency hides under the row copy
            ntok = x[tn];
            nad  = indices[tn];
        }

        const f32x4* __restrict__ wrow =
            (const f32x4*)(weight + (size_t)tok * EMBED);
        f32x4* __restrict__ orow = (f32x4*)(out + (size_t)t * EMBED);

        if (ad >= 0) {
            const f32x4* __restrict__ drow =
                (const f32x4*)(delta_weights +
                               ((size_t)ad * VOCAB + (size_t)tok) * EMBED);
            // 512 float4 chunks / 256 threads = 2 iterations, unrolled for ILP.
            #pragma unroll
            for (int i = 0; i < 2; ++i) {
                const int c = threadIdx.x + i * BLOCK;
                f32x4 w = wrow[c];                                // reusable: cache
                f32x4 d = __builtin_nontemporal_load(&drow[c]);   // read-once: nt
                w += d;
                __builtin_nontemporal_store(w, &orow[c]);         // write-once: nt
            }
        } else {
            #pragma unroll
            for (int i = 0; i < 2; ++i) {
                const int c = threadIdx.x + i * BLOCK;
                __builtin_nontemporal_store(wrow[c], &orow[c]);
            }
        }

        if (!has_next) break;
        t   = tn;
        tok = ntok;
        ad  = nad;
    }
}

extern "C" void kernel_launch(void* const* d_in, const int* in_sizes, int n_in,
                              void* d_out, int out_size, void* d_ws, size_t ws_size,
                              hipStream_t stream) {
    const int*   x             = (const int*)d_in[0];
    const int*   indices       = (const int*)d_in[1];
    const float* weight        = (const float*)d_in[2];
    const float* delta_weights = (const float*)d_in[3];
    float*       out           = (float*)d_out;

    const int num_tokens = in_sizes[0];  // 8192
    const int grid = num_tokens < MAXGRID ? num_tokens : MAXGRID;

    VocabParallelEmbeddingWithDelta_28973849379098_kernel
        <<<grid, BLOCK, 0, stream>>>(x, indices, weight, delta_weights, out,
                                     num_tokens);
}